// Round 6
// baseline (291.960 us; speedup 1.0000x reference)
//
#include <hip/hip_runtime.h>
#include <stdint.h>
#include <stddef.h>

// MASLoRALinear via concatenation identity:
//   hg[b,t,e*16+r] = SCALING * w[b,e] * (x @ As^T)[b,t,e,r]      (gate baked in)
//   out = [x_bf16 | hg] @ [W_base | Bcat]^T + b_base
// Round 9: main_gemm -> phase-split pipelined GEMM. BM=256 BN=128 BK=64,
// 512 thr = 8 waves (2M x 4N), wave out 128x32. Per K-tile: {af0+b reads |
// af1 reads | lgkmcnt(8) | MFMA h0 (overlaps af1 completion) | lgkmcnt(0) |
// barrier | GLL t+2 (prefetch distance 2: ~2500cy cover >> 900cy HBM lat) |
// MFMA h1 (overlaps GLL flight)}. vmcnt(6) counted at tile entry, never 0
// mid-loop. XOR-8 conflict-free LDS (R5: 0 conflicts). 752 blocks = 2.94
// rounds (98% makespan). LDS 96 KB dbuf, 1 block/CU. sched_barrier(0) after
// every counted wait (rule #18). cvt/h_gemm/prep_w unchanged (R5-verified).

#define B_ 16
#define T_ 1500
#define C_ 1024
#define O_ 1024
#define E_ 8
#define R_ 16
#define ER 128     // E*R
#define KK 1152    // C_ + ER
#define BT 24000   // B_*T_
#define NKT 18     // KK / 64 K-tiles
#define SCALING 2.0f

typedef __bf16 bf16x8 __attribute__((ext_vector_type(8)));
typedef float f32x4 __attribute__((ext_vector_type(4)));
typedef unsigned short u16;
typedef u16 u16x8 __attribute__((ext_vector_type(8)));

__device__ inline u16 f2bf(float f) {
  union { float f; unsigned u; } v; v.f = f;
  unsigned u = v.u;
  u += 0x7fff + ((u >> 16) & 1);  // RNE
  return (u16)(u >> 16);
}

#define GLL(gp, lp)                                                            \
  __builtin_amdgcn_global_load_lds(                                            \
      (const __attribute__((address_space(1))) void*)(gp),                     \
      (__attribute__((address_space(3))) void*)(lp), 16, 0, 0)

#define SBAR __builtin_amdgcn_sched_barrier(0)

// ---------------- kernel 1: prep weights ----------------
// wp[o][0:1024]=bf16(W_base), wp[o][1024+e*16+r]=bf16(Bs[e,o,r]); ap=bf16(As flat).
__global__ __launch_bounds__(256) void prep_w(const float* __restrict__ Wb,
                                              const float* __restrict__ Bs,
                                              const float* __restrict__ As,
                                              u16* __restrict__ wp,
                                              u16* __restrict__ ap) {
  int idx = blockIdx.x * 256 + threadIdx.x;
  if (idx < O_ * KK) {
    int o = idx / KK;
    int k = idx - o * KK;
    float v;
    if (k < C_) {
      v = Wb[o * C_ + k];
    } else {
      int j = k - C_;
      v = Bs[((j >> 4) * O_ + o) * R_ + (j & 15)];
    }
    wp[idx] = f2bf(v);
  } else {
    int a = idx - O_ * KK;  // 131,072 elements of As
    ap[a] = f2bf(As[a]);
  }
}

// ---------------- kernel 2a: streaming convert ----------------
// x fp32 (24000x1024) -> xp bf16 cols 0:1024 (row stride 1152). Pure
// memory-roofline: 98 MB read + 47 MB write, no barriers, no LDS.
__global__ __launch_bounds__(256) void cvt(const float* __restrict__ x,
                                           u16* __restrict__ xp) {
  const int t0 = blockIdx.x * 256 + threadIdx.x;  // 0..511999
#pragma unroll
  for (int u = 0; u < 6; ++u) {
    const int chunk = u * 512000 + t0;            // 0..3,071,999
    const int row = chunk >> 7;                   // 0..23999
    const int cc = (chunk & 127) * 8;             // 0..1016
    const float4 v0 = *(const float4*)&x[(size_t)row * C_ + cc];
    const float4 v1 = *(const float4*)&x[(size_t)row * C_ + cc + 4];
    u16x8 o;
    o[0] = f2bf(v0.x); o[1] = f2bf(v0.y); o[2] = f2bf(v0.z); o[3] = f2bf(v0.w);
    o[4] = f2bf(v1.x); o[5] = f2bf(v1.y); o[6] = f2bf(v1.z); o[7] = f2bf(v1.w);
    *(u16x8*)&xp[(size_t)row * KK + cc] = o;
  }
}

// ---------------- kernel 2b: LoRA h-GEMM + gate ----------------
// hg[row, e*16+r] = SCALING * w[b,e] * (x_bf16 @ As^T)  -> xp cols 1024:1152.
// M=24000 (375 x 64-row tiles), N=128, K=1024, BK=64, XOR-8 conflict-free.
__global__ __launch_bounds__(256) void h_gemm(const u16* __restrict__ xp,
                                              const u16* __restrict__ ab,
                                              const float* __restrict__ w,
                                              u16* __restrict__ xpo) {
  const int mt = blockIdx.x;  // 0..374 (exact: 375*64 = 24000)
  const int tid = threadIdx.x, lane = tid & 63, wv = tid >> 6;
  const int wrow = wv & 1, wcol = wv >> 1, l15 = lane & 15, quad = lane >> 4;
  const int s7 = l15 & 7;

  __shared__ u16 lA[64 * 64];    // 8 KB
  __shared__ u16 lB[128 * 64];   // 16 KB

  const u16* gA = xp + (size_t)mt * 64 * KK;

  f32x4 acc[2][4];
#pragma unroll
  for (int i = 0; i < 2; ++i)
#pragma unroll
    for (int j = 0; j < 4; ++j) acc[i][j] = (f32x4){0.f, 0.f, 0.f, 0.f};

  int arow[2], ako[2], brow[4], bko[4];
#pragma unroll
  for (int c = 0; c < 2; ++c) {
    int idx = c * 256 + tid;            // 0..511: row=idx>>3 (0..63)
    arow[c] = idx >> 3;
    ako[c] = (((idx & 7) ^ (arow[c] & 7)) << 3);
  }
#pragma unroll
  for (int c = 0; c < 4; ++c) {
    int idx = c * 256 + tid;            // 0..1023: row=idx>>3 (0..127)
    brow[c] = idx >> 3;
    bko[c] = (((idx & 7) ^ (brow[c] & 7)) << 3);
  }

  for (int kt = 0; kt < C_ / 64; ++kt) {  // 16 iterations
    const int k0 = kt * 64;
#pragma unroll
    for (int c = 0; c < 2; ++c)
      GLL(gA + (size_t)arow[c] * KK + k0 + ako[c], &lA[(c * 256 + tid) * 8]);
#pragma unroll
    for (int c = 0; c < 4; ++c)
      GLL(ab + brow[c] * C_ + k0 + bko[c], &lB[(c * 256 + tid) * 8]);
    __syncthreads();
#pragma unroll
    for (int kk = 0; kk < 2; ++kk) {
      const int ko = (((kk * 4 + quad) ^ s7) << 3);
      bf16x8 af[2], bfr[4];
#pragma unroll
      for (int i = 0; i < 2; ++i)
        af[i] = *(const bf16x8*)&lA[(wrow * 32 + i * 16 + l15) * 64 + ko];
#pragma unroll
      for (int j = 0; j < 4; ++j)
        bfr[j] = *(const bf16x8*)&lB[(wcol * 64 + j * 16 + l15) * 64 + ko];
#pragma unroll
      for (int i = 0; i < 2; ++i)
#pragma unroll
        for (int j = 0; j < 4; ++j)
          acc[i][j] = __builtin_amdgcn_mfma_f32_16x16x32_bf16(af[i], bfr[j], acc[i][j], 0, 0, 0);
    }
    __syncthreads();
  }

  // epilogue: col -> expert e = wcol*4+j (lane-uniform), rank r = l15
#pragma unroll
  for (int j = 0; j < 4; ++j) {
    const int col = wcol * 64 + j * 16 + l15;
    const int e = wcol * 4 + j;
#pragma unroll
    for (int i = 0; i < 2; ++i) {
#pragma unroll
      for (int rr = 0; rr < 4; ++rr) {
        const int row = mt * 64 + wrow * 32 + i * 16 + quad * 4 + rr;
        const int b = row / T_;
        xpo[(size_t)row * KK + C_ + col] = f2bf(acc[i][j][rr] * (SCALING * w[b * E_ + e]));
      }
    }
  }
}

// ---------------- kernel 3: main GEMM (phase-split pipeline) ----------------
// out[row][o] = X'[row,:] . W'[o,:] + b_base[o];  M=24000 K=1152 N=1024.
// BM=256 BN=128 BK=64; 512 thr = 8 waves (wm=wv>>2 in {0,1}, wn=wv&3), wave
// out 128x32 (acc[8][2]). LDS dbuf 96 KB -> 1 block/CU, 2 waves/SIMD.
// Per K-tile t (buf d=t&1), prefetch distance 2:
//   vmcnt(6): tile t landed (only t+1's 6 GLLs outstanding); s_barrier
//   reads: af0 (rows 0..63 of wave, 8x b128) + b (4x b128)  [group 1]
//          af1 (rows 64..127, 8x b128)                       [group 2]
//   lgkmcnt(8): group 1 done, af1 flying -> MFMA h0 (16) overlaps af1
//   lgkmcnt(0): all reads done; s_barrier -> buf d free
//   GLL tile t+2 -> buf d (6); MFMA h1 (16) overlaps GLL flight
// sched_barrier(0) after each counted wait pins MFMA (rule #18); between
// read groups pins ds_read issue order (lgkm counts assume in-order DS).
// XCD-chunked map (752 = 8*94, bijective): xcd id&7 gets 94 consecutive g;
// nt sweeps fastest -> A-panel (590 KB) L2-resident per XCD.
__global__ __launch_bounds__(512, 2) void main_gemm(const u16* __restrict__ xp,
                                                    const u16* __restrict__ wp,
                                                    const float* __restrict__ bb,
                                                    float* __restrict__ out) {
  const int id = blockIdx.x;                 // 0..751
  const int g = (id & 7) * 94 + (id >> 3);   // XCD-chunked tile index
  const int mt = g >> 3;                     // 0..93
  const int nt = g & 7;                      // 0..7
  const int tid = threadIdx.x, lane = tid & 63, wv = tid >> 6;  // 8 waves
  const int wm = wv >> 2, wn = wv & 3, l15 = lane & 15, quad = lane >> 4;
  const int s7 = l15 & 7;

  __shared__ u16 lA[2][256 * 64];  // 2 x 32 KB
  __shared__ u16 lB[2][128 * 64];  // 2 x 16 KB

  const u16* gA = xp + (size_t)mt * 256 * KK;
  const u16* gB = wp + (size_t)nt * 128 * KK;

  f32x4 acc[8][2];
#pragma unroll
  for (int i = 0; i < 8; ++i)
#pragma unroll
    for (int j = 0; j < 2; ++j) acc[i][j] = (f32x4){0.f, 0.f, 0.f, 0.f};

  // staging: A 4 GLL rounds (2048 chunks), B 2 rounds (1024); XOR-8 swizzle:
  // phys chunk p=idx&7 of row idx>>3 holds logical chunk p^(row&7).
  const u16* pA[4];
  const u16* pB[2];
  int dA[4], dB[2];
#pragma unroll
  for (int c = 0; c < 4; ++c) {
    int idx = c * 512 + tid;          // 0..2047: row=idx>>3 (0..255)
    int row = idx >> 3;
    pA[c] = gA + (size_t)row * KK + (((idx & 7) ^ (row & 7)) << 3);
    dA[c] = idx * 8;
  }
#pragma unroll
  for (int c = 0; c < 2; ++c) {
    int idx = c * 512 + tid;          // 0..1023: row=idx>>3 (0..127)
    int row = idx >> 3;
    pB[c] = gB + (size_t)row * KK + (((idx & 7) ^ (row & 7)) << 3);
    dB[c] = idx * 8;
  }

  // prologue: tile0 -> buf0 (6 GLL), tile1 -> buf1 (6 GLL); 12 outstanding
#pragma unroll
  for (int c = 0; c < 4; ++c) GLL(pA[c], &lA[0][dA[c]]);
#pragma unroll
  for (int c = 0; c < 2; ++c) GLL(pB[c], &lB[0][dB[c]]);
#pragma unroll
  for (int c = 0; c < 4; ++c) GLL(pA[c] + 64, &lA[1][dA[c]]);
#pragma unroll
  for (int c = 0; c < 2; ++c) GLL(pB[c] + 64, &lB[1][dB[c]]);

#pragma unroll 2
  for (int t = 0; t < NKT; ++t) {
    const int cur = t & 1;
    if (t < NKT - 1) {
      asm volatile("s_waitcnt vmcnt(6)" ::: "memory");   // tile t landed
    } else {
      asm volatile("s_waitcnt vmcnt(0)" ::: "memory");   // tail drain
    }
    SBAR;
    __builtin_amdgcn_s_barrier();
    SBAR;

    // group 1: af0 (8 reads) + b (4 reads)
    bf16x8 af0[4][2], af1[4][2], bfr[2][2];
#pragma unroll
    for (int ks = 0; ks < 2; ++ks) {
      const int ko = (((ks * 4 + quad) ^ s7) << 3);
#pragma unroll
      for (int i = 0; i < 4; ++i)
        af0[i][ks] = *(const bf16x8*)&lA[cur][(wm * 128 + i * 16 + l15) * 64 + ko];
#pragma unroll
      for (int j = 0; j < 2; ++j)
        bfr[j][ks] = *(const bf16x8*)&lB[cur][(wn * 32 + j * 16 + l15) * 64 + ko];
    }
    SBAR;  // pin issue order: group 1 before group 2
    // group 2: af1 (8 reads)
#pragma unroll
    for (int ks = 0; ks < 2; ++ks) {
      const int ko = (((ks * 4 + quad) ^ s7) << 3);
#pragma unroll
      for (int i = 0; i < 4; ++i)
        af1[i][ks] = *(const bf16x8*)&lA[cur][(wm * 128 + (i + 4) * 16 + l15) * 64 + ko];
    }
    asm volatile("s_waitcnt lgkmcnt(8)" ::: "memory");   // group 1 done, af1 flying
    SBAR;
    __builtin_amdgcn_s_setprio(1);
#pragma unroll
    for (int ks = 0; ks < 2; ++ks)
#pragma unroll
      for (int i = 0; i < 4; ++i)
#pragma unroll
        for (int j = 0; j < 2; ++j)
          acc[i][j] = __builtin_amdgcn_mfma_f32_16x16x32_bf16(af0[i][ks], bfr[j][ks],
                                                              acc[i][j], 0, 0, 0);
    __builtin_amdgcn_s_setprio(0);
    asm volatile("s_waitcnt lgkmcnt(0)" ::: "memory");   // af1 done (all reads done)
    SBAR;
    __builtin_amdgcn_s_barrier();                        // buf[cur] free for t+2
    SBAR;
    if (t + 2 < NKT) {
      const int k2 = (t + 2) * 64;
#pragma unroll
      for (int c = 0; c < 4; ++c) GLL(pA[c] + k2, &lA[cur][dA[c]]);
#pragma unroll
      for (int c = 0; c < 2; ++c) GLL(pB[c] + k2, &lB[cur][dB[c]]);
    }
    __builtin_amdgcn_s_setprio(1);
#pragma unroll
    for (int ks = 0; ks < 2; ++ks)
#pragma unroll
      for (int i = 0; i < 4; ++i)
#pragma unroll
        for (int j = 0; j < 2; ++j)
          acc[i + 4][j] = __builtin_amdgcn_mfma_f32_16x16x32_bf16(af1[i][ks], bfr[j][ks],
                                                                  acc[i + 4][j], 0, 0, 0);
    __builtin_amdgcn_s_setprio(0);
  }

#pragma unroll
  for (int j = 0; j < 2; ++j) {
    const int col = nt * 128 + wn * 32 + j * 16 + l15;
    const float bias = bb[col];
#pragma unroll
    for (int i = 0; i < 8; ++i) {
#pragma unroll
      for (int rr = 0; rr < 4; ++rr) {
        const int row = mt * 256 + wm * 128 + i * 16 + quad * 4 + rr;
        if (row < BT) out[(size_t)row * O_ + col] = acc[i][j][rr] + bias;
      }
    }
  }
}

extern "C" void kernel_launch(void* const* d_in, const int* in_sizes, int n_in,
                              void* d_out, int out_size, void* d_ws, size_t ws_size,
                              hipStream_t stream) {
  const float* x = (const float*)d_in[0];    // (16,1500,1024)
  const float* w = (const float*)d_in[1];    // (16,8)
  const float* Wb = (const float*)d_in[2];   // (1024,1024)
  const float* bb = (const float*)d_in[3];   // (1024,)
  const float* As = (const float*)d_in[4];   // (8,16,1024)
  const float* Bs = (const float*)d_in[5];   // (8,1024,16)
  float* out = (float*)d_out;                // (16,1500,1024) fp32

  // ws: X' (24000x1152 u16, 55.30 MB) | W' (1024x1152 u16, 2.36 MB) | Asb (128x1024 u16, 0.26 MB)
  // main_gemm mt=93 staging over-reads rows 24000..24063 -> land in W' region (allocated, masked).
  u16* xp = (u16*)d_ws;
  u16* wp = xp + (size_t)BT * KK;
  u16* ap = wp + (size_t)O_ * KK;

  prep_w<<<(O_ * KK + ER * C_) / 256, 256, 0, stream>>>(Wb, Bs, As, wp, ap);
  cvt<<<2000, 256, 0, stream>>>(x, xp);
  h_gemm<<<375, 256, 0, stream>>>(xp, ap, w, xp);
  main_gemm<<<752, 512, 0, stream>>>(xp, wp, bb, out);
}

// Round 7
// 275.421 us; speedup vs baseline: 1.0600x; 1.0600x over previous
//
#include <hip/hip_runtime.h>
#include <stdint.h>
#include <stddef.h>

// MASLoRALinear via concatenation identity:
//   hg[b,t,e*16+r] = SCALING * w[b,e] * (x @ As^T)[b,t,e,r]      (gate baked in)
//   out = [x_bf16 | hg] @ [W_base | Bcat]^T + b_base
// Round 10: main_gemm geometry+schedule fix for the diagnosed LDS-read-BW /
// serialization bound (R5 ~= R6 ~= 91 us at MfmaUtil 24%: ds_reads exposed,
// intensity 25.6 FLOP/LDS-byte). Now: BM=192 BN=256, 8 waves (2Mx4N), wave
// 96x64 (intensity 38.4, 0.417 reads/MFMA), 500 blocks (97.7% makespan,
// 125*192=24000 exact -> no masks). Schedule: ALL ds_reads issued under MFMA
// cover (af1_t under h0_t; af0/b_{t+1} under h1_t after BAR2), GLL under
// MFMA, counted vmcnt(7). Two barriers per tile: BAR1 frees buf[cur] for GLL
// t+2; BAR2 publishes tile t+1 (vmcnt is per-wave; cross-wave staged data
// needs barrier-after-everyones-vmcnt). b frags register-double-buffered
// (bfA/bfB) via 2-tile unrolled body (static indexing, rule #20).
// cvt/h_gemm/prep_w unchanged (R5-verified).

#define B_ 16
#define T_ 1500
#define C_ 1024
#define O_ 1024
#define E_ 8
#define R_ 16
#define ER 128     // E*R
#define KK 1152    // C_ + ER
#define BT 24000   // B_*T_
#define NKT 18     // KK / 64 K-tiles
#define SCALING 2.0f

typedef __bf16 bf16x8 __attribute__((ext_vector_type(8)));
typedef float f32x4 __attribute__((ext_vector_type(4)));
typedef unsigned short u16;
typedef u16 u16x8 __attribute__((ext_vector_type(8)));

__device__ inline u16 f2bf(float f) {
  union { float f; unsigned u; } v; v.f = f;
  unsigned u = v.u;
  u += 0x7fff + ((u >> 16) & 1);  // RNE
  return (u16)(u >> 16);
}

#define GLL(gp, lp)                                                            \
  __builtin_amdgcn_global_load_lds(                                            \
      (const __attribute__((address_space(1))) void*)(gp),                     \
      (__attribute__((address_space(3))) void*)(lp), 16, 0, 0)

#define SBAR __builtin_amdgcn_sched_barrier(0)

// ---------------- kernel 1: prep weights ----------------
// wp[o][0:1024]=bf16(W_base), wp[o][1024+e*16+r]=bf16(Bs[e,o,r]); ap=bf16(As flat).
__global__ __launch_bounds__(256) void prep_w(const float* __restrict__ Wb,
                                              const float* __restrict__ Bs,
                                              const float* __restrict__ As,
                                              u16* __restrict__ wp,
                                              u16* __restrict__ ap) {
  int idx = blockIdx.x * 256 + threadIdx.x;
  if (idx < O_ * KK) {
    int o = idx / KK;
    int k = idx - o * KK;
    float v;
    if (k < C_) {
      v = Wb[o * C_ + k];
    } else {
      int j = k - C_;
      v = Bs[((j >> 4) * O_ + o) * R_ + (j & 15)];
    }
    wp[idx] = f2bf(v);
  } else {
    int a = idx - O_ * KK;  // 131,072 elements of As
    ap[a] = f2bf(As[a]);
  }
}

// ---------------- kernel 2a: streaming convert ----------------
// x fp32 (24000x1024) -> xp bf16 cols 0:1024 (row stride 1152). Pure
// memory-roofline: 98 MB read + 47 MB write, no barriers, no LDS.
__global__ __launch_bounds__(256) void cvt(const float* __restrict__ x,
                                           u16* __restrict__ xp) {
  const int t0 = blockIdx.x * 256 + threadIdx.x;  // 0..511999
#pragma unroll
  for (int u = 0; u < 6; ++u) {
    const int chunk = u * 512000 + t0;            // 0..3,071,999
    const int row = chunk >> 7;                   // 0..23999
    const int cc = (chunk & 127) * 8;             // 0..1016
    const float4 v0 = *(const float4*)&x[(size_t)row * C_ + cc];
    const float4 v1 = *(const float4*)&x[(size_t)row * C_ + cc + 4];
    u16x8 o;
    o[0] = f2bf(v0.x); o[1] = f2bf(v0.y); o[2] = f2bf(v0.z); o[3] = f2bf(v0.w);
    o[4] = f2bf(v1.x); o[5] = f2bf(v1.y); o[6] = f2bf(v1.z); o[7] = f2bf(v1.w);
    *(u16x8*)&xp[(size_t)row * KK + cc] = o;
  }
}

// ---------------- kernel 2b: LoRA h-GEMM + gate ----------------
// hg[row, e*16+r] = SCALING * w[b,e] * (x_bf16 @ As^T)  -> xp cols 1024:1152.
// M=24000 (375 x 64-row tiles), N=128, K=1024, BK=64, XOR-8 conflict-free.
__global__ __launch_bounds__(256) void h_gemm(const u16* __restrict__ xp,
                                              const u16* __restrict__ ab,
                                              const float* __restrict__ w,
                                              u16* __restrict__ xpo) {
  const int mt = blockIdx.x;  // 0..374 (exact: 375*64 = 24000)
  const int tid = threadIdx.x, lane = tid & 63, wv = tid >> 6;
  const int wrow = wv & 1, wcol = wv >> 1, l15 = lane & 15, quad = lane >> 4;
  const int s7 = l15 & 7;

  __shared__ u16 lA[64 * 64];    // 8 KB
  __shared__ u16 lB[128 * 64];   // 16 KB

  const u16* gA = xp + (size_t)mt * 64 * KK;

  f32x4 acc[2][4];
#pragma unroll
  for (int i = 0; i < 2; ++i)
#pragma unroll
    for (int j = 0; j < 4; ++j) acc[i][j] = (f32x4){0.f, 0.f, 0.f, 0.f};

  int arow[2], ako[2], brow[4], bko[4];
#pragma unroll
  for (int c = 0; c < 2; ++c) {
    int idx = c * 256 + tid;            // 0..511: row=idx>>3 (0..63)
    arow[c] = idx >> 3;
    ako[c] = (((idx & 7) ^ (arow[c] & 7)) << 3);
  }
#pragma unroll
  for (int c = 0; c < 4; ++c) {
    int idx = c * 256 + tid;            // 0..1023: row=idx>>3 (0..127)
    brow[c] = idx >> 3;
    bko[c] = (((idx & 7) ^ (brow[c] & 7)) << 3);
  }

  for (int kt = 0; kt < C_ / 64; ++kt) {  // 16 iterations
    const int k0 = kt * 64;
#pragma unroll
    for (int c = 0; c < 2; ++c)
      GLL(gA + (size_t)arow[c] * KK + k0 + ako[c], &lA[(c * 256 + tid) * 8]);
#pragma unroll
    for (int c = 0; c < 4; ++c)
      GLL(ab + brow[c] * C_ + k0 + bko[c], &lB[(c * 256 + tid) * 8]);
    __syncthreads();
#pragma unroll
    for (int kk = 0; kk < 2; ++kk) {
      const int ko = (((kk * 4 + quad) ^ s7) << 3);
      bf16x8 af[2], bfr[4];
#pragma unroll
      for (int i = 0; i < 2; ++i)
        af[i] = *(const bf16x8*)&lA[(wrow * 32 + i * 16 + l15) * 64 + ko];
#pragma unroll
      for (int j = 0; j < 4; ++j)
        bfr[j] = *(const bf16x8*)&lB[(wcol * 64 + j * 16 + l15) * 64 + ko];
#pragma unroll
      for (int i = 0; i < 2; ++i)
#pragma unroll
        for (int j = 0; j < 4; ++j)
          acc[i][j] = __builtin_amdgcn_mfma_f32_16x16x32_bf16(af[i], bfr[j], acc[i][j], 0, 0, 0);
    }
    __syncthreads();
  }

  // epilogue: col -> expert e = wcol*4+j (lane-uniform), rank r = l15
#pragma unroll
  for (int j = 0; j < 4; ++j) {
    const int col = wcol * 64 + j * 16 + l15;
    const int e = wcol * 4 + j;
#pragma unroll
    for (int i = 0; i < 2; ++i) {
#pragma unroll
      for (int rr = 0; rr < 4; ++rr) {
        const int row = mt * 64 + wrow * 32 + i * 16 + quad * 4 + rr;
        const int b = row / T_;
        xpo[(size_t)row * KK + C_ + col] = f2bf(acc[i][j][rr] * (SCALING * w[b * E_ + e]));
      }
    }
  }
}

// ---------------- kernel 3: main GEMM (reads-under-MFMA pipeline) ----------------
// out[row][o] = X'[row,:] . W'[o,:] + b_base[o];  M=24000 K=1152 N=1024.
// BM=192 BN=256 BK=64; 512 thr = 8 waves (2M x 4N), wave out 96x64:
// acc[6][4], per tile 20 ds_read -> 48 MFMA (0.417 reads/MFMA).
// Per K-tile t (cur=t&1), prefetch distance 2 (7 GLL/wave/tile):
//   [issue af1_t | MFMA h0_t (24: af0 x b)]   <- af1 reads fly under h0
//   lgkm(0); BAR1                              <- buf[cur] fully read
//   GLL t+2 -> buf[cur]; vmcnt(7)              <- own t+1 GLLs landed
//   BAR2                                       <- ALL waves' t+1 landed
//   [issue af0_{t+1}, b_{t+1} from buf[nxt] | MFMA h1_t (24: af1 x b)]
// b register-double-buffered (bfA even tiles, bfB odd); af0/af1 single-set
// (dead after their half). 500 blocks (125 mt x 4 nt, exact M), 1 block/CU
// (LDS 112 KB), bijective XCD-chunked map (m204: q=62 r=4).
__global__ __launch_bounds__(512, 2) void main_gemm(const u16* __restrict__ xp,
                                                    const u16* __restrict__ wp,
                                                    const float* __restrict__ bb,
                                                    float* __restrict__ out) {
  const int id = blockIdx.x;                 // 0..499
  const int xcd = id & 7, win = id >> 3;
  const int g = (xcd < 4 ? xcd * 63 : 252 + (xcd - 4) * 62) + win;
  const int mt = g >> 2;                     // 0..124
  const int nt = g & 3;                      // 0..3
  const int tid = threadIdx.x, lane = tid & 63, wv = tid >> 6;  // 8 waves
  const int wm = wv >> 2, wn = wv & 3, l15 = lane & 15, quad = lane >> 4;
  const int s7 = l15 & 7;
  const int ko0 = (quad ^ s7) << 3;          // ks=0 logical chunk = quad
  const int ko1 = ((4 + quad) ^ s7) << 3;    // ks=1 logical chunk = 4+quad

  __shared__ u16 lA[2][192 * 64];  // 2 x 24 KB
  __shared__ u16 lB[2][256 * 64];  // 2 x 32 KB   (total 112 KB)

  const u16* gA = xp + (size_t)mt * 192 * KK;
  const u16* gB = wp + (size_t)nt * 256 * KK;

  f32x4 acc[6][4];
#pragma unroll
  for (int i = 0; i < 6; ++i)
#pragma unroll
    for (int j = 0; j < 4; ++j) acc[i][j] = (f32x4){0.f, 0.f, 0.f, 0.f};

  // staging: A 3 GLL rounds (1536 chunks), B 4 rounds (2048); XOR-8 swizzle.
  const u16* pA[3];
  const u16* pB[4];
  int dA[3], dB[4];
#pragma unroll
  for (int c = 0; c < 3; ++c) {
    int idx = c * 512 + tid;          // row = idx>>3 (0..191)
    int row = idx >> 3;
    pA[c] = gA + (size_t)row * KK + (((idx & 7) ^ (row & 7)) << 3);
    dA[c] = idx * 8;
  }
#pragma unroll
  for (int c = 0; c < 4; ++c) {
    int idx = c * 512 + tid;          // row = idx>>3 (0..255)
    int row = idx >> 3;
    pB[c] = gB + (size_t)row * KK + (((idx & 7) ^ (row & 7)) << 3);
    dB[c] = idx * 8;
  }

#define ROWA(i) ((wm * 96 + (i) * 16 + l15) * 64)
#define ROWB(j) ((wn * 64 + (j) * 16 + l15) * 64)

  // prologue: tile0 -> buf0, tile1 -> buf1 (14 GLL outstanding)
#pragma unroll
  for (int c = 0; c < 3; ++c) GLL(pA[c], &lA[0][dA[c]]);
#pragma unroll
  for (int c = 0; c < 4; ++c) GLL(pB[c], &lB[0][dB[c]]);
#pragma unroll
  for (int c = 0; c < 3; ++c) GLL(pA[c] + 64, &lA[1][dA[c]]);
#pragma unroll
  for (int c = 0; c < 4; ++c) GLL(pB[c] + 64, &lB[1][dB[c]]);
  asm volatile("s_waitcnt vmcnt(7)" ::: "memory");  // tile0 landed (own)
  SBAR;
  __builtin_amdgcn_s_barrier();                     // all waves' tile0 landed
  SBAR;

  bf16x8 af0[3][2], af1[3][2], bfA[4][2], bfB[4][2];
#pragma unroll
  for (int i = 0; i < 3; ++i) {
    af0[i][0] = *(const bf16x8*)&lA[0][ROWA(i) + ko0];
    af0[i][1] = *(const bf16x8*)&lA[0][ROWA(i) + ko1];
  }
#pragma unroll
  for (int j = 0; j < 4; ++j) {
    bfA[j][0] = *(const bf16x8*)&lB[0][ROWB(j) + ko0];
    bfA[j][1] = *(const bf16x8*)&lB[0][ROWB(j) + ko1];
  }

  // body macro: CUR = LDS parity of tile t; BC = b frags of tile t;
  // BN_ = b frags of tile t+1 (read from buf[CUR^1]).
#define TILE_BODY(T, CUR, BC, BN_)                                             \
  {                                                                            \
    const int t_ = (T);                                                        \
    _Pragma("unroll")                                                          \
    for (int i = 0; i < 3; ++i) {                                              \
      af1[i][0] = *(const bf16x8*)&lA[CUR][ROWA(i + 3) + ko0];                 \
      af1[i][1] = *(const bf16x8*)&lA[CUR][ROWA(i + 3) + ko1];                 \
    }                                                                          \
    __builtin_amdgcn_s_setprio(1);                                             \
    _Pragma("unroll")                                                          \
    for (int ks = 0; ks < 2; ++ks)                                             \
      _Pragma("unroll")                                                        \
      for (int i = 0; i < 3; ++i)                                              \
        _Pragma("unroll")                                                      \
        for (int j = 0; j < 4; ++j)                                            \
          acc[i][j] = __builtin_amdgcn_mfma_f32_16x16x32_bf16(                 \
              af0[i][ks], BC[j][ks], acc[i][j], 0, 0, 0);                      \
    __builtin_amdgcn_s_setprio(0);                                             \
    asm volatile("s_waitcnt lgkmcnt(0)" ::: "memory");                         \
    SBAR;                                                                      \
    __builtin_amdgcn_s_barrier(); /* BAR1: buf[CUR] fully read */              \
    SBAR;                                                                      \
    if (t_ + 2 < NKT) {                                                        \
      const int k2 = (t_ + 2) * 64;                                            \
      _Pragma("unroll")                                                        \
      for (int c = 0; c < 3; ++c) GLL(pA[c] + k2, &lA[CUR][dA[c]]);            \
      _Pragma("unroll")                                                        \
      for (int c = 0; c < 4; ++c) GLL(pB[c] + k2, &lB[CUR][dB[c]]);            \
      asm volatile("s_waitcnt vmcnt(7)" ::: "memory");                         \
    } else {                                                                   \
      asm volatile("s_waitcnt vmcnt(0)" ::: "memory");                         \
    }                                                                          \
    SBAR;                                                                      \
    __builtin_amdgcn_s_barrier(); /* BAR2: tile t+1 visible to all waves */    \
    SBAR;                                                                      \
    if (t_ + 1 < NKT) {                                                        \
      _Pragma("unroll")                                                        \
      for (int i = 0; i < 3; ++i) {                                            \
        af0[i][0] = *(const bf16x8*)&lA[CUR ^ 1][ROWA(i) + ko0];               \
        af0[i][1] = *(const bf16x8*)&lA[CUR ^ 1][ROWA(i) + ko1];               \
      }                                                                        \
      _Pragma("unroll")                                                        \
      for (int j = 0; j < 4; ++j) {                                            \
        BN_[j][0] = *(const bf16x8*)&lB[CUR ^ 1][ROWB(j) + ko0];               \
        BN_[j][1] = *(const bf16x8*)&lB[CUR ^ 1][ROWB(j) + ko1];               \
      }                                                                        \
    }                                                                          \
    __builtin_amdgcn_s_setprio(1);                                             \
    _Pragma("unroll")                                                          \
    for (int ks = 0; ks < 2; ++ks)                                             \
      _Pragma("unroll")                                                        \
      for (int i = 0; i < 3; ++i)                                              \
        _Pragma("unroll")                                                      \
        for (int j = 0; j < 4; ++j)                                            \
          acc[i + 3][j] = __builtin_amdgcn_mfma_f32_16x16x32_bf16(             \
              af1[i][ks], BC[j][ks], acc[i + 3][j], 0, 0, 0);                  \
    __builtin_amdgcn_s_setprio(0);                                             \
  }

  for (int tt = 0; tt < 9; ++tt) {
    TILE_BODY(2 * tt, 0, bfA, bfB)      // even tile: buf0, b in bfA, next -> bfB
    TILE_BODY(2 * tt + 1, 1, bfB, bfA)  // odd tile: buf1, b in bfB, next -> bfA
  }
#undef TILE_BODY
#undef ROWA
#undef ROWB

  // epilogue: 125*192 = 24000 exact -> no row mask
#pragma unroll
  for (int j = 0; j < 4; ++j) {
    const int col = nt * 256 + wn * 64 + j * 16 + l15;
    const float bias = bb[col];
#pragma unroll
    for (int i = 0; i < 6; ++i) {
#pragma unroll
      for (int rr = 0; rr < 4; ++rr) {
        const int row = mt * 192 + wm * 96 + i * 16 + quad * 4 + rr;
        out[(size_t)row * O_ + col] = acc[i][j][rr] + bias;
      }
    }
  }
}

extern "C" void kernel_launch(void* const* d_in, const int* in_sizes, int n_in,
                              void* d_out, int out_size, void* d_ws, size_t ws_size,
                              hipStream_t stream) {
  const float* x = (const float*)d_in[0];    // (16,1500,1024)
  const float* w = (const float*)d_in[1];    // (16,8)
  const float* Wb = (const float*)d_in[2];   // (1024,1024)
  const float* bb = (const float*)d_in[3];   // (1024,)
  const float* As = (const float*)d_in[4];   // (8,16,1024)
  const float* Bs = (const float*)d_in[5];   // (8,1024,16)
  float* out = (float*)d_out;                // (16,1500,1024) fp32

  // ws: X' (24000x1152 u16, 55.30 MB) | W' (1024x1152 u16, 2.36 MB) | Asb (128x1024 u16, 0.26 MB)
  u16* xp = (u16*)d_ws;
  u16* wp = xp + (size_t)BT * KK;
  u16* ap = wp + (size_t)O_ * KK;

  prep_w<<<(O_ * KK + ER * C_) / 256, 256, 0, stream>>>(Wb, Bs, As, wp, ap);
  cvt<<<2000, 256, 0, stream>>>(x, xp);
  h_gemm<<<375, 256, 0, stream>>>(xp, ap, w, xp);
  main_gemm<<<500, 512, 0, stream>>>(xp, wp, bb, out);
}